// Round 1
// baseline (213.624 us; speedup 1.0000x reference)
//
#include <hip/hip_runtime.h>

// AssocScan: out[:, t] = gates[:, t] * out[:, t-1] + inputs[:, t]
// Shapes: (B, N, D) = (4, 4096, 1024), fp32, scan over axis 1 (N).
// Layout is row-major so D is contiguous -> scans are independent per (b,d),
// and lanes over consecutive d are perfectly coalesced at each timestep.
//
// 3-phase chunked scan (no inter-block dependencies):
//   phase1: per (b, chunk, d4) compute chunk aggregate (A = prod g, KV = local scan end)
//   phase2: per (b, d4) serial exclusive scan over chunk aggregates -> carry per chunk
//   phase3: per (b, chunk, d4) redo local recurrence starting from carry, write out.

namespace {
constexpr int kB = 4;
constexpr int kN = 4096;
constexpr int kD = 1024;
constexpr int kChunks = 128;
constexpr int kT = kN / kChunks;          // 32 timesteps per chunk
constexpr int kD4 = kD / 4;               // 256 float4 channel-groups
constexpr int kAgg = kB * kChunks * kD4;  // 131072 float4 aggregates
}  // namespace

__global__ __launch_bounds__(256) void assoc_scan_phase1(
    const float4* __restrict__ g, const float4* __restrict__ x,
    float4* __restrict__ Ag, float4* __restrict__ Kv) {
  const int gid = blockIdx.x * 256 + threadIdx.x;   // 0 .. kAgg-1
  const int d4 = gid & (kD4 - 1);                   // channel group (fastest -> coalesced)
  const int c  = (gid >> 8) & (kChunks - 1);        // chunk
  const int b  = gid >> 15;                         // batch
  // float4 index of (b, t=c*kT, d=d4*4)
  int idx = (b * kN + c * kT) * kD4 + d4;

  float4 a  = make_float4(1.f, 1.f, 1.f, 1.f);
  float4 kv = make_float4(0.f, 0.f, 0.f, 0.f);
#pragma unroll 4
  for (int i = 0; i < kT; ++i, idx += kD4) {
    const float4 gv = g[idx];
    const float4 xv = x[idx];
    a.x *= gv.x; a.y *= gv.y; a.z *= gv.z; a.w *= gv.w;
    kv.x = fmaf(gv.x, kv.x, xv.x);
    kv.y = fmaf(gv.y, kv.y, xv.y);
    kv.z = fmaf(gv.z, kv.z, xv.z);
    kv.w = fmaf(gv.w, kv.w, xv.w);
  }
  Ag[gid] = a;
  Kv[gid] = kv;
}

__global__ __launch_bounds__(256) void assoc_scan_phase2(
    const float4* __restrict__ Ag, const float4* __restrict__ Kv,
    float4* __restrict__ carry) {
  const int gid = blockIdx.x * 256 + threadIdx.x;   // 0 .. kB*kD4-1
  const int d4 = gid & (kD4 - 1);
  const int b  = gid >> 8;

  float4 h = make_float4(0.f, 0.f, 0.f, 0.f);
  for (int c = 0; c < kChunks; ++c) {
    const int idx = (b * kChunks + c) * kD4 + d4;
    carry[idx] = h;                                  // exclusive: carry INTO chunk c
    const float4 a  = Ag[idx];
    const float4 kv = Kv[idx];
    h.x = fmaf(a.x, h.x, kv.x);
    h.y = fmaf(a.y, h.y, kv.y);
    h.z = fmaf(a.z, h.z, kv.z);
    h.w = fmaf(a.w, h.w, kv.w);
  }
}

__global__ __launch_bounds__(256) void assoc_scan_phase3(
    const float4* __restrict__ g, const float4* __restrict__ x,
    const float4* __restrict__ carry, float4* __restrict__ out) {
  const int gid = blockIdx.x * 256 + threadIdx.x;   // 0 .. kAgg-1
  const int d4 = gid & (kD4 - 1);
  const int c  = (gid >> 8) & (kChunks - 1);
  const int b  = gid >> 15;
  int idx = (b * kN + c * kT) * kD4 + d4;

  float4 h = carry[gid];
#pragma unroll 4
  for (int i = 0; i < kT; ++i, idx += kD4) {
    const float4 gv = g[idx];
    const float4 xv = x[idx];
    h.x = fmaf(gv.x, h.x, xv.x);
    h.y = fmaf(gv.y, h.y, xv.y);
    h.z = fmaf(gv.z, h.z, xv.z);
    h.w = fmaf(gv.w, h.w, xv.w);
    out[idx] = h;
  }
}

extern "C" void kernel_launch(void* const* d_in, const int* in_sizes, int n_in,
                              void* d_out, int out_size, void* d_ws, size_t ws_size,
                              hipStream_t stream) {
  const float4* g = (const float4*)d_in[0];   // gates  (B,N,D) fp32
  const float4* x = (const float4*)d_in[1];   // inputs (B,N,D) fp32
  float4* out = (float4*)d_out;

  // Workspace: 3 arrays of kAgg float4 (2 MiB each, 6 MiB total)
  float4* Ag    = (float4*)d_ws;
  float4* Kv    = Ag + kAgg;
  float4* carry = Kv + kAgg;

  assoc_scan_phase1<<<kAgg / 256, 256, 0, stream>>>(g, x, Ag, Kv);
  assoc_scan_phase2<<<(kB * kD4) / 256, 256, 0, stream>>>(Ag, Kv, carry);
  assoc_scan_phase3<<<kAgg / 256, 256, 0, stream>>>(g, x, carry, out);
}

// Round 3
// 200.415 us; speedup vs baseline: 1.0659x; 1.0659x over previous
//
#include <hip/hip_runtime.h>

// AssocScan: out[:, t] = gates[:, t] * out[:, t-1] + inputs[:, t]
// (B, N, D) = (4, 4096, 1024) fp32, scan over N, D contiguous.
//
// 3-phase chunked scan, tuned for occupancy:
//   phase1: T=8 timesteps/thread, 512 chunks -> 8192 waves (100% wave capacity).
//           Each thread: chunk aggregate (A = prod g, KV = local scan end).
//   phase2: one WAVE per (b,d4) column: 8 chunks/lane serial combine,
//           6-step shfl Kogge-Stone wave scan, write per-chunk carry (h-value).
//           carry aliases Ag in workspace (reads precede writes per thread,
//           index sets disjoint across threads).
//   phase3: re-run recurrence from carry, write out (re-read hits LLC).
//
// R2 bug fixed: phase2 grid must be kB*kD4/4 blocks (one wave per column),
// was /256 (left 1008/1024 columns with garbage carries).

namespace {
constexpr int kB = 4;
constexpr int kN = 4096;
constexpr int kD = 1024;
constexpr int kChunks = 512;
constexpr int kT = kN / kChunks;            // 8 timesteps per chunk
constexpr int kD4 = kD / 4;                 // 256 float4 channel-groups
constexpr int kAgg = kB * kChunks * kD4;    // 524288 float4 aggregates (8 MiB each arr)
constexpr int kCPL = kChunks / 64;          // 8 chunks per lane in phase2
}  // namespace

__device__ __forceinline__ float4 shfl_up4(float4 v, int off) {
  float4 r;
  r.x = __shfl_up(v.x, off);
  r.y = __shfl_up(v.y, off);
  r.z = __shfl_up(v.z, off);
  r.w = __shfl_up(v.w, off);
  return r;
}

__global__ __launch_bounds__(256) void assoc_scan_phase1(
    const float4* __restrict__ g, const float4* __restrict__ x,
    float4* __restrict__ Ag, float4* __restrict__ Kv) {
  const int gid = blockIdx.x * 256 + threadIdx.x;   // 0 .. kAgg-1
  const int d4 = gid & (kD4 - 1);                   // fastest -> coalesced
  const int c  = (gid >> 8) & (kChunks - 1);
  const int b  = gid >> 17;
  int idx = (b * kN + c * kT) * kD4 + d4;

  float4 a  = make_float4(1.f, 1.f, 1.f, 1.f);
  float4 kv = make_float4(0.f, 0.f, 0.f, 0.f);
#pragma unroll
  for (int i = 0; i < kT; ++i, idx += kD4) {
    const float4 gv = g[idx];
    const float4 xv = x[idx];
    a.x *= gv.x; a.y *= gv.y; a.z *= gv.z; a.w *= gv.w;
    kv.x = fmaf(gv.x, kv.x, xv.x);
    kv.y = fmaf(gv.y, kv.y, xv.y);
    kv.z = fmaf(gv.z, kv.z, xv.z);
    kv.w = fmaf(gv.w, kv.w, xv.w);
  }
  Ag[gid] = a;
  Kv[gid] = kv;
}

// One wave per (b, d4) column; scans kChunks aggregates, writes carry (h into chunk).
__global__ __launch_bounds__(256) void assoc_scan_phase2(
    const float4* __restrict__ Ag, const float4* __restrict__ Kv,
    float4* __restrict__ carry) {
  const int lane = threadIdx.x & 63;
  const int col  = blockIdx.x * 4 + (threadIdx.x >> 6);  // 0 .. kB*kD4-1
  const int d4 = col & (kD4 - 1);
  const int b  = col >> 8;
  const int cBase = lane * kCPL;

  // local serial combine over this lane's 8 chunks, keeping exclusive prefixes
  float4 la[kCPL], lk[kCPL];
  float4 ra = make_float4(1.f, 1.f, 1.f, 1.f);
  float4 rk = make_float4(0.f, 0.f, 0.f, 0.f);
#pragma unroll
  for (int i = 0; i < kCPL; ++i) {
    const int idx = (b * kChunks + cBase + i) * kD4 + d4;
    la[i] = ra; lk[i] = rk;
    const float4 a = Ag[idx];
    const float4 k = Kv[idx];
    rk.x = fmaf(a.x, rk.x, k.x);
    rk.y = fmaf(a.y, rk.y, k.y);
    rk.z = fmaf(a.z, rk.z, k.z);
    rk.w = fmaf(a.w, rk.w, k.w);
    ra.x *= a.x; ra.y *= a.y; ra.z *= a.z; ra.w *= a.w;
  }

  // wave-wide Kogge-Stone inclusive scan of (ra, rk); lower lane = "first"
#pragma unroll
  for (int off = 1; off < 64; off <<= 1) {
    const float4 pa = shfl_up4(ra, off);
    const float4 pk = shfl_up4(rk, off);
    if (lane >= off) {
      rk.x = fmaf(ra.x, pk.x, rk.x);
      rk.y = fmaf(ra.y, pk.y, rk.y);
      rk.z = fmaf(ra.z, pk.z, rk.z);
      rk.w = fmaf(ra.w, pk.w, rk.w);
      ra.x *= pa.x; ra.y *= pa.y; ra.z *= pa.z; ra.w *= pa.w;
    }
  }
  // exclusive wave prefix
  float4 ek = shfl_up4(rk, 1);
  if (lane == 0) {
    ek = make_float4(0.f, 0.f, 0.f, 0.f);
  }

  // carry into chunk cBase+i = KV of combine(wave_excl, local_excl[i])
#pragma unroll
  for (int i = 0; i < kCPL; ++i) {
    const int idx = (b * kChunks + cBase + i) * kD4 + d4;
    float4 ck;
    ck.x = fmaf(la[i].x, ek.x, lk[i].x);
    ck.y = fmaf(la[i].y, ek.y, lk[i].y);
    ck.z = fmaf(la[i].z, ek.z, lk[i].z);
    ck.w = fmaf(la[i].w, ek.w, lk[i].w);
    carry[idx] = ck;
  }
}

__global__ __launch_bounds__(256) void assoc_scan_phase3(
    const float4* __restrict__ g, const float4* __restrict__ x,
    const float4* __restrict__ carry, float4* __restrict__ out) {
  const int gid = blockIdx.x * 256 + threadIdx.x;
  const int d4 = gid & (kD4 - 1);
  const int c  = (gid >> 8) & (kChunks - 1);
  const int b  = gid >> 17;
  int idx = (b * kN + c * kT) * kD4 + d4;

  float4 h = carry[gid];
#pragma unroll
  for (int i = 0; i < kT; ++i, idx += kD4) {
    const float4 gv = g[idx];
    const float4 xv = x[idx];
    h.x = fmaf(gv.x, h.x, xv.x);
    h.y = fmaf(gv.y, h.y, xv.y);
    h.z = fmaf(gv.z, h.z, xv.z);
    h.w = fmaf(gv.w, h.w, xv.w);
    out[idx] = h;
  }
}

extern "C" void kernel_launch(void* const* d_in, const int* in_sizes, int n_in,
                              void* d_out, int out_size, void* d_ws, size_t ws_size,
                              hipStream_t stream) {
  const float4* g = (const float4*)d_in[0];   // gates  (B,N,D) fp32
  const float4* x = (const float4*)d_in[1];   // inputs (B,N,D) fp32
  float4* out = (float4*)d_out;

  // Workspace: Ag (8 MiB) + Kv (8 MiB). carry aliases Ag — safe: in phase2 each
  // thread reads all its Ag entries before writing carry at those same indices,
  // and index sets are disjoint across threads.
  float4* Ag    = (float4*)d_ws;
  float4* Kv    = Ag + kAgg;
  float4* carry = Ag;

  assoc_scan_phase1<<<kAgg / 256, 256, 0, stream>>>(g, x, Ag, Kv);
  // one wave per column: kB*kD4 = 1024 columns, 4 waves (cols) per 256-thread block
  assoc_scan_phase2<<<(kB * kD4) / 4, 256, 0, stream>>>(Ag, Kv, carry);
  assoc_scan_phase3<<<kAgg / 256, 256, 0, stream>>>(g, x, carry, out);
}